// Round 1
// baseline (201.821 us; speedup 1.0000x reference)
//
#include <hip/hip_runtime.h>
#include <hip/hip_bf16.h>
#include <stdint.h>
#include <stddef.h>

// MDCT: out[b,k,o] = sum_t x[b, o*512-512+t] * f[k,t], t in [0,1024), zero-pad OOB.
// Fold identity: c(t) = -c(N-1-t) on [0,N), c(t) = c(3N-1-t) on [N,2N)
//   => K halves: out = D[512x512] . V[512 x cols], V folded from x.
// Precision: bf16x3 split GEMM (Dh*Vh + Dh*Vl + Dl*Vh) ~ fp32 accuracy.

constexpr int N_ = 512;
constexpr int T_ = 2048;
constexpr int B_ = 16;
constexpr int LEN = N_ * T_;           // 1048576 samples per batch
constexpr int FRAMES = T_ + 1;         // 2049
constexpr int COLS = B_ * FRAMES;      // 32784
constexpr int NT_TILES = 257;          // ceil(COLS/128)
constexpr int COLS_PAD = NT_TILES * 128; // 32896
constexpr int KF = 512;                // folded K

typedef __attribute__((ext_vector_type(8))) short bf16x8;
typedef __attribute__((ext_vector_type(4))) float f32x4;

#define GLD16(gptr, lptr)                                                     \
  __builtin_amdgcn_global_load_lds(                                           \
      (const __attribute__((address_space(1))) unsigned int*)(gptr),          \
      (__attribute__((address_space(3))) unsigned int*)(lptr), 16, 0, 0)

// ---------------- Kernel 1: gather + split filter ---------------------------
// D[k][j] = f[k][j] (j<256) or f[k][j+256] (j>=256); split into bf16 hi/lo.
__global__ void prep_filter(const float* __restrict__ f,
                            __hip_bfloat16* __restrict__ Dh,
                            __hip_bfloat16* __restrict__ Dl) {
  int idx = blockIdx.x * 256 + threadIdx.x;   // 512*512 total
  int k = idx >> 9;
  int j = idx & 511;
  int t = (j < 256) ? j : (j + 256);
  float d = f[k * 1024 + t];
  __hip_bfloat16 h = __float2bfloat16(d);
  __hip_bfloat16 l = __float2bfloat16(d - __bfloat162float(h));
  Dh[k * KF + j] = h;
  Dl[k * KF + j] = l;
}

// ---------------- Kernel 2: fold x -> V (column-major, bf16 hi/lo) ----------
__global__ void fold_x(const float* __restrict__ x,
                       __hip_bfloat16* __restrict__ Vh,
                       __hip_bfloat16* __restrict__ Vl) {
  int c = blockIdx.x;                          // 0 .. COLS_PAD-1
  int j = blockIdx.y * 256 + threadIdx.x;      // 0 .. 511
  float v = 0.0f;
  if (c < COLS) {
    int b = c / FRAMES;
    int o = c - b * FRAMES;
    const float* xb = x + (size_t)b * LEN;
    int g = o * N_ - N_;
    int i0, i1;
    float s;
    if (j < 256) { i0 = g + j;       i1 = g + 511 - j;  s = -1.0f; }
    else         { i0 = g + j + 256; i1 = g + 1279 - j; s =  1.0f; }
    float a  = (i0 >= 0 && i0 < LEN) ? xb[i0] : 0.0f;
    float bv = (i1 >= 0 && i1 < LEN) ? xb[i1] : 0.0f;
    v = a + s * bv;
  }
  __hip_bfloat16 h = __float2bfloat16(v);
  __hip_bfloat16 l = __float2bfloat16(v - __bfloat162float(h));
  Vh[(size_t)c * KF + j] = h;
  Vl[(size_t)c * KF + j] = l;
}

// ---------------- Kernel 3: C[512, cols] = D . V, bf16x3 MFMA ---------------
// 128x128 block tile, BK=32, 4 waves (2x2 of 64x64), mfma_f32_16x16x32_bf16.
__global__ __launch_bounds__(256, 2) void gemm_fold(
    const __hip_bfloat16* __restrict__ Dh, const __hip_bfloat16* __restrict__ Dl,
    const __hip_bfloat16* __restrict__ Vh, const __hip_bfloat16* __restrict__ Vl,
    float* __restrict__ out) {
  __shared__ __hip_bfloat16 Ah[128 * 32];
  __shared__ __hip_bfloat16 Al[128 * 32];
  __shared__ __hip_bfloat16 Bh[128 * 32];
  __shared__ __hip_bfloat16 Bl[128 * 32];

  const int m0g = blockIdx.x * 128;  // 4 m-tiles (fast-varying: share B tile in L2)
  const int n0g = blockIdx.y * 128;  // 257 n-tiles
  const int tid = threadIdx.x;
  const int wid = tid >> 6;
  const int lane = tid & 63;
  const int quad = lane >> 4;
  const int l16 = lane & 15;
  const int mw = (wid >> 1) * 64;
  const int nw = (wid & 1) * 64;

  f32x4 acc[4][4];
#pragma unroll
  for (int i = 0; i < 4; ++i)
#pragma unroll
    for (int j = 0; j < 4; ++j) acc[i][j] = (f32x4){0.f, 0.f, 0.f, 0.f};

  for (int kt = 0; kt < 16; ++kt) {
    const int kb = kt * 32;
    __syncthreads();  // all waves done reading previous tile
#pragma unroll
    for (int it = 0; it < 2; ++it) {
      const int e = (wid * 2 + it) * 64 + lane;  // 16B-chunk id, 0..511
      const int row = e >> 2;                    // 0..127
      const int ks = (e & 3) * 8;                // 0,8,16,24
      const int ldoff = e * 8;                   // bf16 elems == e*16 bytes
      GLD16(Dh + (size_t)(m0g + row) * KF + kb + ks, &Ah[ldoff]);
      GLD16(Dl + (size_t)(m0g + row) * KF + kb + ks, &Al[ldoff]);
      GLD16(Vh + (size_t)(n0g + row) * KF + kb + ks, &Bh[ldoff]);
      GLD16(Vl + (size_t)(n0g + row) * KF + kb + ks, &Bl[ldoff]);
    }
    __syncthreads();  // drains vmcnt: LDS tiles ready

    bf16x8 ah[4], al[4], bh[4], bl[4];
#pragma unroll
    for (int i = 0; i < 4; ++i) {
      ah[i] = *(const bf16x8*)&Ah[(mw + i * 16 + l16) * 32 + quad * 8];
      al[i] = *(const bf16x8*)&Al[(mw + i * 16 + l16) * 32 + quad * 8];
      bh[i] = *(const bf16x8*)&Bh[(nw + i * 16 + l16) * 32 + quad * 8];
      bl[i] = *(const bf16x8*)&Bl[(nw + i * 16 + l16) * 32 + quad * 8];
    }
#pragma unroll
    for (int i = 0; i < 4; ++i)
#pragma unroll
      for (int j = 0; j < 4; ++j) {
        acc[i][j] = __builtin_amdgcn_mfma_f32_16x16x32_bf16(ah[i], bh[j], acc[i][j], 0, 0, 0);
        acc[i][j] = __builtin_amdgcn_mfma_f32_16x16x32_bf16(ah[i], bl[j], acc[i][j], 0, 0, 0);
        acc[i][j] = __builtin_amdgcn_mfma_f32_16x16x32_bf16(al[i], bh[j], acc[i][j], 0, 0, 0);
      }
  }

  // Epilogue: C/D layout col=lane&15, row=quad*4+reg. col -> (batch, frame).
#pragma unroll
  for (int i = 0; i < 4; ++i) {
#pragma unroll
    for (int j = 0; j < 4; ++j) {
      int col = n0g + nw + j * 16 + l16;
      if (col < COLS) {
        int b = col / FRAMES;
        int o = col - b * FRAMES;
        int rowb = m0g + mw + i * 16 + quad * 4;
        float* op = out + (size_t)b * N_ * FRAMES + (size_t)rowb * FRAMES + o;
#pragma unroll
        for (int r = 0; r < 4; ++r) op[(size_t)r * FRAMES] = acc[i][j][r];
      }
    }
  }
}

// ---------------- Fallback: direct fp32 conv (if ws too small) --------------
__global__ void naive_conv(const float* __restrict__ x, const float* __restrict__ f,
                           float* __restrict__ out) {
  int col = blockIdx.x;  // 0..COLS-1
  int k = threadIdx.x;   // 0..511
  __shared__ float win[1024];
  int b = col / FRAMES;
  int o = col - b * FRAMES;
  const float* xb = x + (size_t)b * LEN;
  int g = o * N_ - N_;
  for (int t = threadIdx.x; t < 1024; t += 512) {
    int i = g + t;
    win[t] = (i >= 0 && i < LEN) ? xb[i] : 0.0f;
  }
  __syncthreads();
  float s = 0.0f;
  const float* fk = f + (size_t)k * 1024;
  for (int t = 0; t < 1024; ++t) s += win[t] * fk[t];
  out[(size_t)b * N_ * FRAMES + (size_t)k * FRAMES + o] = s;
}

extern "C" void kernel_launch(void* const* d_in, const int* in_sizes, int n_in,
                              void* d_out, int out_size, void* d_ws, size_t ws_size,
                              hipStream_t stream) {
  const float* x = (const float*)d_in[0];
  const float* f = (const float*)d_in[1];
  float* out = (float*)d_out;

  const size_t elems_D = (size_t)512 * 512;          // per split
  const size_t elems_V = (size_t)COLS_PAD * KF;      // per split
  const size_t need = (2 * elems_D + 2 * elems_V) * sizeof(__hip_bfloat16);

  if (ws_size < need) {
    naive_conv<<<COLS, 512, 0, stream>>>(x, f, out);
    return;
  }

  __hip_bfloat16* Dh = (__hip_bfloat16*)d_ws;
  __hip_bfloat16* Dl = Dh + elems_D;
  __hip_bfloat16* Vh = Dl + elems_D;
  __hip_bfloat16* Vl = Vh + elems_V;

  prep_filter<<<1024, 256, 0, stream>>>(f, Dh, Dl);
  fold_x<<<dim3(COLS_PAD, 2), 256, 0, stream>>>(x, Vh, Vl);
  gemm_fold<<<dim3(4, NT_TILES), 256, 0, stream>>>(Dh, Dl, Vh, Vl, out);
}

// Round 2
// 148.669 us; speedup vs baseline: 1.3575x; 1.3575x over previous
//
#include <hip/hip_runtime.h>
#include <hip/hip_bf16.h>
#include <stdint.h>
#include <stddef.h>

// MDCT as folded GEMM: out[512, 32784] = D[512,512] . V[512, 32784]
//   fold: j<256:  v = x[g+j] - x[g+511-j]
//         j>=256: v = x[g+j+256] + x[g+1279-j],  g = o*512 - 512
// Precision: single fp16 product (2^-11 taps); measured round-1 absmax 0.03125
// was bf16-ulp quantization grain, not GEMM precision -> headroom exists.

constexpr int N_ = 512;
constexpr int T_ = 2048;
constexpr int B_ = 16;
constexpr int LEN = N_ * T_;              // 1048576
constexpr int FRAMES = T_ + 1;            // 2049
constexpr int COLS = B_ * FRAMES;         // 32784
constexpr int NT_TILES = 257;
constexpr int COLS_PAD = NT_TILES * 128;  // 32896
constexpr int KF = 512;
constexpr int BK = 64;

typedef __attribute__((ext_vector_type(8))) _Float16 f16x8;
typedef __attribute__((ext_vector_type(4))) _Float16 f16x4;
typedef __attribute__((ext_vector_type(4))) float f32x4;

#define GLD16(gptr, lptr)                                                     \
  __builtin_amdgcn_global_load_lds(                                           \
      (const __attribute__((address_space(1))) unsigned int*)(gptr),          \
      (__attribute__((address_space(3))) unsigned int*)(lptr), 16, 0, 0)

// ---------------- Kernel 1: gather filter -> fp16 D -------------------------
__global__ void prep_filter(const float* __restrict__ f,
                            _Float16* __restrict__ D) {
  int idx = (blockIdx.x * 256 + threadIdx.x) * 4;  // 512*512 elems, 4/thread
  int k = idx >> 9;
  int j = idx & 511;
  int t = (j < 256) ? j : (j + 256);               // j..j+3 same branch (j%4==0)
  const float4 v = *(const float4*)&f[k * 1024 + t];
  f16x4 h = {(_Float16)v.x, (_Float16)v.y, (_Float16)v.z, (_Float16)v.w};
  *(f16x4*)&D[k * KF + j] = h;
}

// ---------------- Kernel 2: fold x -> V fp16, column-major ------------------
// block=256: two columns per block; 128 threads/column; 4 j per thread.
__global__ void fold_x(const float* __restrict__ x, _Float16* __restrict__ V) {
  const int half = threadIdx.x >> 7;      // which column of the pair
  const int t = threadIdx.x & 127;        // 0..127
  const int c = blockIdx.x * 2 + half;
  int jbase;
  float4 va = {0.f, 0.f, 0.f, 0.f}, vb = {0.f, 0.f, 0.f, 0.f};
  float s;
  if (t < 64) { jbase = t * 4; s = -1.0f; }            // wave-uniform branch
  else        { jbase = 256 + (t - 64) * 4; s = 1.0f; }
  if (c < COLS) {
    int b = c / FRAMES;
    int o = c - b * FRAMES;
    const float* xb = x + (size_t)b * LEN;
    int g = o * N_ - N_;
    int i0, i1r;
    if (t < 64) { i0 = g + jbase;       i1r = g + 508 - jbase; }
    else        { int u = t - 64; i0 = g + 512 + u * 4; i1r = g + 1020 - u * 4; }
    // boundary frames: each float4 window is fully in or fully out (verified)
    if ((unsigned)i0 <= (unsigned)(LEN - 4))  va = *(const float4*)&xb[i0];
    if ((unsigned)i1r <= (unsigned)(LEN - 4)) vb = *(const float4*)&xb[i1r];
  }
  f16x4 h;
  h[0] = (_Float16)(va.x + s * vb.w);
  h[1] = (_Float16)(va.y + s * vb.z);
  h[2] = (_Float16)(va.z + s * vb.y);
  h[3] = (_Float16)(va.w + s * vb.x);
  *(f16x4*)&V[(size_t)c * KF + jbase] = h;
}

// ---------------- Kernel 3: C = D . V, fp16 MFMA, swizzled LDS --------------
// 128x128 tile, BK=64, 4 waves (2x2 of 64x64), mfma_f32_16x16x32_f16.
// LDS slot map: row r (0..127) x chunk c (0..7, 16B each); slot = r*8 + (c ^ (r&7)).
// GLD16 dest is base+lane*16, so the swizzle is applied by permuting WHICH
// global chunk each lane fetches. Fragment reads then hit 8 distinct bank
// quads per 16 lanes (2-way aliasing = free) instead of 8-way conflicts.
__global__ __launch_bounds__(256, 4) void gemm_fold(
    const _Float16* __restrict__ D, const _Float16* __restrict__ V,
    float* __restrict__ out) {
  __shared__ __align__(16) _Float16 As[128 * BK];
  __shared__ __align__(16) _Float16 Bs[128 * BK];

  const int m0 = blockIdx.x * 128;   // 4 m-tiles (fast axis)
  const int n0 = blockIdx.y * 128;   // 257 n-tiles
  const int tid = threadIdx.x;
  const int wid = tid >> 6;
  const int lane = tid & 63;
  const int quad = lane >> 4;
  const int l16 = lane & 15;
  const int mw = (wid >> 1) * 64;
  const int nw = (wid & 1) * 64;

  f32x4 acc[4][4];
#pragma unroll
  for (int i = 0; i < 4; ++i)
#pragma unroll
    for (int j = 0; j < 4; ++j) acc[i][j] = (f32x4){0.f, 0.f, 0.f, 0.f};

  for (int kt = 0; kt < KF / BK; ++kt) {  // 8 iterations
    const int kb = kt * BK;
    __syncthreads();  // previous tile fully consumed
#pragma unroll
    for (int it = 0; it < 4; ++it) {
      const int S = it * 256 + tid;          // LDS slot = uniform base + lane
      const int r = S >> 3;                  // tile row
      const int c = (S & 7) ^ (r & 7);       // swizzled global chunk
      const int goff = kb + c * 8;           // halves
      GLD16(D + (size_t)(m0 + r) * KF + goff, &As[S * 8]);
      GLD16(V + (size_t)(n0 + r) * KF + goff, &Bs[S * 8]);
    }
    __syncthreads();  // drains vmcnt: tiles ready

#pragma unroll
    for (int ko = 0; ko < 2; ++ko) {
      f16x8 af[4], bf[4];
#pragma unroll
      for (int i = 0; i < 4; ++i) {
        int ra = mw + i * 16 + l16;
        int rb = nw + i * 16 + l16;
        int ca = ko * 4 + quad;
        af[i] = *(const f16x8*)&As[(ra * 8 + (ca ^ (ra & 7))) * 8];
        bf[i] = *(const f16x8*)&Bs[(rb * 8 + (ca ^ (rb & 7))) * 8];
      }
#pragma unroll
      for (int i = 0; i < 4; ++i)
#pragma unroll
        for (int j = 0; j < 4; ++j)
          acc[i][j] = __builtin_amdgcn_mfma_f32_16x16x32_f16(af[i], bf[j], acc[i][j], 0, 0, 0);
    }
  }

  // Epilogue: C/D layout col = lane&15, row = quad*4 + reg (verified round 1).
#pragma unroll
  for (int i = 0; i < 4; ++i) {
#pragma unroll
    for (int j = 0; j < 4; ++j) {
      int col = n0 + nw + j * 16 + l16;
      if (col < COLS) {
        int b = col / FRAMES;
        int o = col - b * FRAMES;
        int rowb = m0 + mw + i * 16 + quad * 4;
        float* op = out + (size_t)b * N_ * FRAMES + (size_t)rowb * FRAMES + o;
#pragma unroll
        for (int r = 0; r < 4; ++r) op[(size_t)r * FRAMES] = acc[i][j][r];
      }
    }
  }
}

// ---------------- Fallback: direct fp32 conv (if ws too small) --------------
__global__ void naive_conv(const float* __restrict__ x, const float* __restrict__ f,
                           float* __restrict__ out) {
  int col = blockIdx.x;
  int k = threadIdx.x;
  __shared__ float win[1024];
  int b = col / FRAMES;
  int o = col - b * FRAMES;
  const float* xb = x + (size_t)b * LEN;
  int g = o * N_ - N_;
  for (int t = threadIdx.x; t < 1024; t += 512) {
    int i = g + t;
    win[t] = (i >= 0 && i < LEN) ? xb[i] : 0.0f;
  }
  __syncthreads();
  float s = 0.0f;
  const float* fk = f + (size_t)k * 1024;
  for (int t = 0; t < 1024; ++t) s += win[t] * fk[t];
  out[(size_t)b * N_ * FRAMES + (size_t)k * FRAMES + o] = s;
}

extern "C" void kernel_launch(void* const* d_in, const int* in_sizes, int n_in,
                              void* d_out, int out_size, void* d_ws, size_t ws_size,
                              hipStream_t stream) {
  const float* x = (const float*)d_in[0];
  const float* f = (const float*)d_in[1];
  float* out = (float*)d_out;

  const size_t elems_D = (size_t)512 * 512;
  const size_t elems_V = (size_t)COLS_PAD * KF;
  const size_t need = (elems_D + elems_V) * sizeof(_Float16);

  if (ws_size < need) {
    naive_conv<<<COLS, 512, 0, stream>>>(x, f, out);
    return;
  }

  _Float16* D = (_Float16*)d_ws;
  _Float16* V = D + elems_D;

  prep_filter<<<256, 256, 0, stream>>>(f, D);
  fold_x<<<COLS_PAD / 2, 256, 0, stream>>>(x, V);
  gemm_fold<<<dim3(4, NT_TILES), 256, 0, stream>>>(D, V, out);
}